// Round 1
// baseline (542.689 us; speedup 1.0000x reference)
//
#include <hip/hip_runtime.h>
#include <math.h>

#define NB 32
#define NT 512
#define NC 4233
#define NU 64
#define LABT 129            // 2*NU+1
#define PADV (-3.4028234663852886e38f)   // float32 min (matches jnp.finfo(f32).min)
#define SCANBLK 192
#define EMIT_N (NB * NT * LABT)          // 2,113,536 floats = 8.45 MB

// ---------------------------------------------------------------------------
// Kernel 0: build ext_idx[b][j], cond[b][j], yl[b]
// ---------------------------------------------------------------------------
__global__ void ctc_prep_kernel(const int* __restrict__ label,   // [U][B]
                                const int* __restrict__ blank_ptr,
                                int* __restrict__ ext_idx,        // [B][LABT]
                                int* __restrict__ cond,           // [B][LABT]
                                int* __restrict__ yl)             // [B]
{
    const int b = blockIdx.x;
    const int j = threadIdx.x;
    const int blank = blank_ptr[0];

    // yl = 2 * count(label != blank) + 1, via wave-0 ballot (U == 64 == wave size)
    if (j < 64) {
        int raw = label[j * NB + b];
        unsigned long long m = __ballot(raw != blank);
        if (j == 0) yl[b] = 2 * (int)__popcll(m) + 1;
    }

    if (j < LABT) {
        int extv;
        if ((j & 1) == 0) {
            extv = blank;
        } else {
            int raw = label[((j - 1) >> 1) * NB + b];
            extv = (raw == blank) ? -1 : raw;
        }
        int sh2;  // ext shifted right by 2, pad -1
        if (j < 2) {
            sh2 = -1;
        } else if (((j - 2) & 1) == 0) {
            sh2 = blank;
        } else {
            int raw2 = label[((j - 3) >> 1) * NB + b];
            sh2 = (raw2 == blank) ? -1 : raw2;
        }
        int c = (extv == blank) || (extv == sh2);
        int idx = extv % NC;            // python floor-mod for -1 pad labels
        if (idx < 0) idx += NC;
        ext_idx[b * LABT + j] = idx;
        cond[b * LABT + j]    = c;
    }
}

// ---------------------------------------------------------------------------
// Kernel 1: massively-parallel emission gather.
// emit[b][t][j] = logit[b][t][ext_idx[b][j]].  All the scattered-HBM latency
// lands here, hidden by ~8k concurrent blocks instead of a 32-block serial
// chain.
// ---------------------------------------------------------------------------
__global__ __launch_bounds__(256)
void ctc_gather_kernel(const float* __restrict__ logit,   // [B][T][C]
                       const int*   __restrict__ ext_idx, // [B][LABT]
                       float*       __restrict__ emit)    // [B][T][LABT]
{
    int tid = blockIdx.x * 256 + threadIdx.x;
    if (tid >= EMIT_N) return;
    int bt = tid / LABT;             // b*NT + t
    int j  = tid - bt * LABT;
    int b  = bt / NT;
    int col = ext_idx[b * LABT + j]; // L2-hot after first touch
    emit[tid] = logit[(size_t)bt * NC + col];
}

// ---------------------------------------------------------------------------
// Kernel 2: forward DP scan over compact emit + loss + register-ring Viterbi
// backtrack + fused one-hot align write.  One block per batch.
// ---------------------------------------------------------------------------
__global__ __launch_bounds__(SCANBLK)
void ctc_scan_kernel(const float* __restrict__ emit,    // [B][T][LABT]
                     const int*   __restrict__ cond,    // [B][LABT]
                     const int*   __restrict__ yl,      // [B]
                     float* __restrict__ out,           // [B][T][LABT] align
                     float* __restrict__ loss_out)      // [B]
{
    __shared__ float dbuf[2][SCANBLK + 8];
    __shared__ __align__(16) unsigned long long bpm[NT][3][2];  // 2-bit backptr
    __shared__ int wl[NT];

    const int b = blockIdx.x;
    const int j = threadIdx.x;
    const bool act = (j < LABT);
    const int jc = act ? j : 0;                       // clamp inactive lanes
    const int cnd = act ? cond[b * LABT + j] : 1;

    const float* eb = emit + (size_t)b * (NT * LABT);

    float* pa = dbuf[0];
    float* pb = dbuf[1];

    // t = 0 init: dp0[0] = emit[0][0], dp0[1] = emit[0][1], else PAD
    float e0 = eb[jc];
    pa[j] = (j <= 1) ? e0 : PADV;

    // prefetch ring for t = 1..4 (contiguous, L2/L3-resident rows)
    float r0 = eb[1 * LABT + jc];
    float r1 = eb[2 * LABT + jc];
    float r2 = eb[3 * LABT + jc];
    float r3 = eb[4 * LABT + jc];
    __syncthreads();

#define STEP(tcur, rr, tload)                                                  \
    do {                                                                       \
        float a  = pa[j];                                                      \
        float b1 = (j >= 1) ? pa[j - 1] : PADV;                                \
        float c2 = (j >= 2) ? pa[j - 2] : PADV;                                \
        float c2e = cnd ? PADV : c2;  /* 2-way lse == 3-way lse with PAD */    \
        float m  = fmaxf(fmaxf(a, b1), c2e);                                   \
        float lse = m + logf(expf(a - m) + expf(b1 - m) + expf(c2e - m));      \
        int delta = (a >= b1 && a >= c2e) ? 0 : ((b1 >= c2e) ? 1 : 2);         \
        pb[j] = rr + lse;                                                      \
        unsigned long long mm0 = __ballot(delta & 1);                          \
        unsigned long long mm1 = __ballot(delta >> 1);                         \
        if ((j & 63) == 0) {                                                   \
            bpm[tcur][j >> 6][0] = mm0;                                        \
            bpm[tcur][j >> 6][1] = mm1;                                        \
        }                                                                      \
        if ((tload) < NT) rr = eb[(tload) * LABT + jc];                        \
        __syncthreads();                                                       \
        float* tpp = pa; pa = pb; pb = tpp;                                    \
    } while (0)

    int t = 1;
    for (; t + 3 < NT; t += 4) {
        STEP(t,     r0, t + 4);
        STEP(t + 1, r1, t + 5);
        STEP(t + 2, r2, t + 6);
        STEP(t + 3, r3, t + 7);
    }
    // tail: t = 509, 510, 511
    STEP(t,     r0, NT);
    STEP(t + 1, r1, NT);
    STEP(t + 2, r2, NT);
#undef STEP

    // pa now holds dp[T-1].  Backtrack: bpm[t] addresses are independent of w,
    // so prefetch whole 48B rows into a 4-slot register ring; the dependent
    // chain is register-only cndmask selects instead of 511 serial LDS reads.
    if (j == 0) {
        int Y = yl[b];
        float d1 = pa[Y - 1];
        float d2 = pa[Y - 2];
        float mm = fmaxf(d1, d2);
        float la = mm + logf(expf(d1 - mm) + expf(d2 - mm));
        loss_out[b] = -la * 2.0f / (float)(Y - 1);

        int w = (d1 > d2) ? (Y - 1) : (Y - 2);
        const ulonglong2* bp2 = (const ulonglong2*)&bpm[0][0][0];  // 3 per row

#define BLOAD(s0, s1, s2, row) do {                                            \
        const ulonglong2* rp_ = bp2 + 3 * (row);                               \
        s0 = rp_[0]; s1 = rp_[1]; s2 = rp_[2];                                 \
    } while (0)
#define BPROC(qa, qb, qc, row) do {                                            \
        wl[row] = w;                                                           \
        int wv_ = w >> 6, ln_ = w & 63;                                        \
        unsigned long long m0_ = (wv_ == 0) ? qa.x : (wv_ == 1) ? qb.x : qc.x; \
        unsigned long long m1_ = (wv_ == 0) ? qa.y : (wv_ == 1) ? qb.y : qc.y; \
        w -= (int)((m0_ >> ln_) & 1ULL) + 2 * (int)((m1_ >> ln_) & 1ULL);      \
    } while (0)

        ulonglong2 q00, q01, q02, q10, q11, q12, q20, q21, q22, q30, q31, q32;
        BLOAD(q00, q01, q02, NT - 1);
        BLOAD(q10, q11, q12, NT - 2);
        BLOAD(q20, q21, q22, NT - 3);
        BLOAD(q30, q31, q32, NT - 4);
        int tt;
        for (tt = NT - 1; tt >= 8; tt -= 4) {
            BPROC(q00, q01, q02, tt    ); BLOAD(q00, q01, q02, tt - 4);
            BPROC(q10, q11, q12, tt - 1); BLOAD(q10, q11, q12, tt - 5);
            BPROC(q20, q21, q22, tt - 2); BLOAD(q20, q21, q22, tt - 6);
            BPROC(q30, q31, q32, tt - 3); BLOAD(q30, q31, q32, tt - 7);
        }
        // slots now hold rows 7,6,5,4
        BPROC(q00, q01, q02, 7); BLOAD(q00, q01, q02, 3);
        BPROC(q10, q11, q12, 6); BLOAD(q10, q11, q12, 2);
        BPROC(q20, q21, q22, 5); BLOAD(q20, q21, q22, 1);
        BPROC(q30, q31, q32, 4);
        BPROC(q00, q01, q02, 3);
        BPROC(q10, q11, q12, 2);
        BPROC(q20, q21, q22, 1);
        wl[0] = w;   // bp at t=0 is identity
#undef BLOAD
#undef BPROC
    }
    __syncthreads();

    // fused one-hot align write: block b owns contiguous out[b*NT*LABT ..)
    float* outA = out + (size_t)b * (NT * LABT);
    for (int p = j; p < NT * LABT; p += SCANBLK) {   // 66048/192 = 344 exact
        int tr = p / LABT;
        int jj = p - tr * LABT;
        outA[p] = (jj == wl[tr]) ? 1.0f : 0.0f;
    }
}

// ---------------------------------------------------------------------------
extern "C" void kernel_launch(void* const* d_in, const int* in_sizes, int n_in,
                              void* d_out, int out_size, void* d_ws, size_t ws_size,
                              hipStream_t stream)
{
    const float* logit = (const float*)d_in[0];
    const int*   label = (const int*)d_in[1];
    const int*   blank = (const int*)d_in[2];

    float* out = (float*)d_out;   // [B*T*LABT] align (0/1 float) then [B] loss

    float* emit    = (float*)d_ws;                 // 8.45 MB
    int*   ext_idx = (int*)(emit + EMIT_N);        // 4128 ints
    int*   cond    = ext_idx + NB * LABT;          // 4128 ints
    int*   yl      = cond + NB * LABT;             // 32 ints

    ctc_prep_kernel<<<NB, SCANBLK, 0, stream>>>(label, blank, ext_idx, cond, yl);
    ctc_gather_kernel<<<EMIT_N / 256, 256, 0, stream>>>(logit, ext_idx, emit);
    ctc_scan_kernel<<<NB, SCANBLK, 0, stream>>>(emit, cond, yl, out, out + EMIT_N);
}